// Round 12
// baseline (329.382 us; speedup 1.0000x reference)
//
#include <hip/hip_runtime.h>
#include <stdint.h>

// ClusterHead: P = softmax_k( x . c_k - 0.5*||c_k||^2 )   (||x||^2 cancels)
// R12: column-split pair blocks + first-exits/second-merges handshake.
// Block 2t+ch: rows [t*64,+64), cols [ch*512,+512). acc[2][2]=64 regs ->
// 4 waves/SIMD, 2 blocks/CU (store drain + latency overlap across blocks).
// Each block: partial softmax over its 512 cols; writes fp16 exp-vals into
// the spare bytes of its own out region (courier) + {m,s} stats to ws;
// atomicAdd(flag): first arriver EXITS (no spin -> no deadlock risk);
// second merges stats, reads both couriers, writes all 1024 cols as
// vectorized f32x4 NT stores. fp16 courier err <=5e-4; role-independent.
// Single-term fp16 GEMM (R10-validated), 32x32x16 f16 MFMA, A-panel staged
// once to LDS (XOR swizzle), barrier-free K-loop (R11-validated).

namespace {
constexpr int N_ROWS  = 32768;
constexpr int K_CL    = 1024;
constexpr int D_DIM   = 512;
constexpr int BM      = 64;
constexpr int THREADS = 512;
constexpr int WAVES   = 8;
constexpr int NTILE   = 512;    // row tiles
}

typedef _Float16 f16_t;
typedef _Float16 f16x8 __attribute__((ext_vector_type(8)));
typedef _Float16 f16x4 __attribute__((ext_vector_type(4)));
typedef float    f32x16 __attribute__((ext_vector_type(16)));
typedef float    f32x4v __attribute__((ext_vector_type(4)));

// ---- prep: fp16 B-pack + bias = -0.5*||c||^2 (fp32 exact) ----
// sub-image s = 2t + jh (k-slice t, col-half jh), 32KB each;
// within: [ks(2)][cb(16)][(c32*2+kh)*8] halfwords.
__global__ __launch_bounds__(64) void prep_kernel(const float* __restrict__ centers,
                                                  f16_t* __restrict__ bpack,
                                                  float* __restrict__ bias) {
  const int col = blockIdx.x, lane = threadIdx.x;
  const int t  = lane >> 2;
  const int ks = (lane >> 1) & 1;
  const int kh = lane & 1;
  const float* src = centers + (size_t)col * D_DIM + lane * 8;
  f16x8 hi;
  float ssq = 0.f;
  #pragma unroll
  for (int i = 0; i < 8; ++i) {
    float v = src[i];
    ssq += v * v;
    hi[i] = (f16_t)v;
  }
  const int jh = col >> 9, cb = (col & 511) >> 5, c32 = col & 31;
  const size_t off = ((size_t)ks * 16 + cb) * 512 + (c32 * 2 + kh) * 8;
  *(f16x8*)(bpack + (size_t)(2 * t + jh) * 16384 + off) = hi;
  for (int o = 32; o; o >>= 1) ssq += __shfl_down(ssq, o, 64);
  if (lane == 0) bias[col] = -0.5f * ssq;
}

// ---- main kernel: 64 rows x 512 cols per block; pair-merge epilogue ----
__global__ __launch_bounds__(THREADS, 4) void cluster_kernel(
    const float* __restrict__ x, const f16_t* __restrict__ bpack,
    const float* __restrict__ bias, float* __restrict__ out,
    float2* __restrict__ stats, int* __restrict__ flags) {
  __shared__ __align__(16) char Ax[65536];   // 64KB swizzled A panel
  __shared__ float red[WAVES * BM];          // 2KB
  __shared__ float fm[BM];
  __shared__ float ffac[2][BM];
  __shared__ int role;

  const int bid  = blockIdx.x;
  const int tile = bid >> 1, ch = bid & 1;
  const int tid  = threadIdx.x;
  const int wid  = tid >> 6;
  const int lane = tid & 63;
  const int l31  = lane & 31;
  const int h    = lane >> 5;
  const int brow = tile * BM;

  const char* bbase = (const char*)bpack + wid * 2048 + (l31 * 2 + h) * 16;
  f16x8 bcur[4], bnxt[4], a[2][2];

#define LOADB4(S, DST)                                                         \
  {                                                                            \
    const char* p_ = bbase + (size_t)(S) * 32768;                              \
    (DST)[0] = *(const f16x8*)(p_);                                            \
    (DST)[1] = *(const f16x8*)(p_ + 1024);                                     \
    (DST)[2] = *(const f16x8*)(p_ + 16384);                                    \
    (DST)[3] = *(const f16x8*)(p_ + 17408);                                    \
  }
#define LOADA(T)                                                               \
  {                                                                            \
    const int o0_ = ((T) * 64 + h * 16) ^ swz;                                 \
    const int o1_ = o0_ ^ 32;                                                  \
    a[0][0] = *(const f16x8*)(abase0 + o0_);                                   \
    a[0][1] = *(const f16x8*)(abase0 + o1_);                                   \
    a[1][0] = *(const f16x8*)(abase0 + 32768 + o0_);                           \
    a[1][1] = *(const f16x8*)(abase0 + 32768 + o1_);                           \
  }
#define COMPUTE8(B)                                                            \
  {                                                                            \
    _Pragma("unroll")                                                          \
    for (int ks_ = 0; ks_ < 2; ++ks_)                                          \
      _Pragma("unroll")                                                        \
      for (int c2_ = 0; c2_ < 2; ++c2_)                                        \
        _Pragma("unroll")                                                      \
        for (int rb_ = 0; rb_ < 2; ++rb_)                                      \
          acc[rb_][c2_] = __builtin_amdgcn_mfma_f32_32x32x16_f16(              \
              a[rb_][ks_], (B)[ks_ * 2 + c2_], acc[rb_][c2_], 0, 0, 0);        \
  }

  LOADB4(ch, bcur)   // first slice's B in flight during staging

  // ---- stage A panel -> LDS fp16 (coalesced reads, swizzled writes) ----
  {
    const float* xsrc = x + (size_t)brow * D_DIM;
    #pragma unroll
    for (int it = 0; it < 16; ++it) {
      const int idx = it * 512 + tid;
      const int r = idx >> 7, f = idx & 127;
      f32x4v v = *(const f32x4v*)(xsrc + (size_t)r * D_DIM + f * 4);
      f16x4 h4;
      h4[0] = (f16_t)v[0]; h4[1] = (f16_t)v[1];
      h4[2] = (f16_t)v[2]; h4[3] = (f16_t)v[3];
      *(f16x4*)(Ax + r * 1024 + ((f * 8) ^ ((r & 7) << 4))) = h4;
    }
  }
  __syncthreads();

  f32x16 acc[2][2];
  #pragma unroll
  for (int rb = 0; rb < 2; ++rb)
    #pragma unroll
    for (int c2 = 0; c2 < 2; ++c2)
      #pragma unroll
      for (int e = 0; e < 16; ++e) acc[rb][c2][e] = 0.f;

  const char* abase0 = Ax + l31 * 1024;
  const int swz = (l31 & 7) << 4;

  // ---- K loop: 16 slices, barrier-free, reg double-buffered B ----
  #pragma unroll
  for (int tt = 0; tt < 8; ++tt) {
    {
      const int T = 2 * tt;
      LOADB4(2 * (T + 1) + ch, bnxt)
      LOADA(T)
      COMPUTE8(bcur)
    }
    {
      const int T = 2 * tt + 1;
      if (T < 15) { LOADB4(2 * (T + 1) + ch, bcur) }
      LOADA(T)
      COMPUTE8(bnxt)
    }
  }

  // ---- partial softmax over this block's 512 cols ----
  // col(c2) = ch*512 + wid*64 + c2*32 + l31 ; row(rb,reg) = rb*32+(reg&3)+8*(reg>>2)+4*h
  float bcol[2];
  #pragma unroll
  for (int c2 = 0; c2 < 2; ++c2)
    bcol[c2] = bias[ch * 512 + wid * 64 + c2 * 32 + l31];

  float rr[2][16];
  #pragma unroll
  for (int rb = 0; rb < 2; ++rb)
    #pragma unroll
    for (int reg = 0; reg < 16; ++reg) {
      float v0 = acc[rb][0][reg] + bcol[0];
      float v1 = acc[rb][1][reg] + bcol[1];
      acc[rb][0][reg] = v0;
      acc[rb][1][reg] = v1;
      float m = fmaxf(v0, v1);
      m = fmaxf(m, __shfl_xor(m, 1, 64));
      m = fmaxf(m, __shfl_xor(m, 2, 64));
      m = fmaxf(m, __shfl_xor(m, 4, 64));
      m = fmaxf(m, __shfl_xor(m, 8, 64));
      m = fmaxf(m, __shfl_xor(m, 16, 64));
      rr[rb][reg] = m;
    }
  if (l31 == 0) {
    #pragma unroll
    for (int rb = 0; rb < 2; ++rb)
      #pragma unroll
      for (int reg = 0; reg < 16; ++reg)
        red[wid * BM + rb * 32 + (reg & 3) + 8 * (reg >> 2) + 4 * h] = rr[rb][reg];
  }
  __syncthreads();
  if (tid < BM) {
    float m = red[tid];
    #pragma unroll
    for (int w = 1; w < WAVES; ++w) m = fmaxf(m, red[w * BM + tid]);
    fm[tid] = m;
  }
  __syncthreads();

  #pragma unroll
  for (int rb = 0; rb < 2; ++rb)
    #pragma unroll
    for (int reg = 0; reg < 16; ++reg) {
      const float m = fm[rb * 32 + (reg & 3) + 8 * (reg >> 2) + 4 * h];
      float e0 = __expf(acc[rb][0][reg] - m);
      float e1 = __expf(acc[rb][1][reg] - m);
      acc[rb][0][reg] = e0;
      acc[rb][1][reg] = e1;
      float s = e0 + e1;
      s += __shfl_xor(s, 1, 64);
      s += __shfl_xor(s, 2, 64);
      s += __shfl_xor(s, 4, 64);
      s += __shfl_xor(s, 8, 64);
      s += __shfl_xor(s, 16, 64);
      rr[rb][reg] = s;
    }
  __syncthreads();   // fm reads done before red overwrite
  if (l31 == 0) {
    #pragma unroll
    for (int rb = 0; rb < 2; ++rb)
      #pragma unroll
      for (int reg = 0; reg < 16; ++reg)
        red[wid * BM + rb * 32 + (reg & 3) + 8 * (reg >> 2) + 4 * h] = rr[rb][reg];
  }
  __syncthreads();
  if (tid < BM) {
    float s = 0.f;
    #pragma unroll
    for (int w = 0; w < WAVES; ++w) s += red[w * BM + tid];
    stats[tile * 128 + ch * 64 + tid] = make_float2(fm[tid], s);
  }

  // ---- courier: fp16 exp-vals into spare bytes of OWN out region ----
  // region of (row, half hf): floats [ (brow+row)*1024 + hf*512 , +512 );
  // courier = f16 indices [512,1024) of that region (bytes 1024..2048).
  #pragma unroll
  for (int rb = 0; rb < 2; ++rb)
    #pragma unroll
    for (int reg = 0; reg < 16; ++reg) {
      const int row = rb * 32 + (reg & 3) + 8 * (reg >> 2) + 4 * h;
      f16_t* cp = (f16_t*)(out + (size_t)(brow + row) * K_CL + ch * 512);
      #pragma unroll
      for (int c2 = 0; c2 < 2; ++c2)
        cp[512 + wid * 64 + c2 * 32 + l31] = (f16_t)acc[rb][c2][reg];
    }
  __syncthreads();   // vmcnt(0) drain: courier + stats retired to L2

  if (tid == 0) {
    __threadfence();                       // release (wbL2)
    role = atomicAdd(&flags[tile], 1);
    __threadfence();                       // acquire (invL2)
  }
  __syncthreads();
  if (role == 0) return;                   // first arriver exits; no spin

  // ---- SECOND: merge stats, finalize both halves ----
  if (tid < BM) {
    float2 sm = stats[tile * 128 + ch * 64 + tid];
    float2 sp = stats[tile * 128 + (1 - ch) * 64 + tid];
    float M  = fmaxf(sm.x, sp.x);
    float eM = __expf(sm.x - M), eP = __expf(sp.x - M);
    float S  = sm.y * eM + sp.y * eP;      // commutative: role-independent bits
    ffac[ch][tid]     = eM / S;
    ffac[1 - ch][tid] = eP / S;
  }
  __syncthreads();

  // read both couriers fully, then overwrite with fp32 (read-before-write)
  const int prow = tid >> 3, pc0 = (tid & 7) * 64;
  f16x8 cv[2][8];
  #pragma unroll
  for (int hf = 0; hf < 2; ++hf) {
    const f16_t* cp =
        (const f16_t*)(out + (size_t)(brow + prow) * K_CL + hf * 512) + 512 + pc0;
    #pragma unroll
    for (int i = 0; i < 8; ++i) cv[hf][i] = *(const f16x8*)(cp + i * 8);
  }
  __syncthreads();   // ALL courier reads complete before ANY fp32 store

  #pragma unroll
  for (int hf = 0; hf < 2; ++hf) {
    const float fac = ffac[hf][prow];
    float* op = out + (size_t)(brow + prow) * K_CL + hf * 512 + pc0;
    #pragma unroll
    for (int i = 0; i < 8; ++i) {
      f32x4v w0, w1;
      w0[0] = (float)cv[hf][i][0] * fac; w0[1] = (float)cv[hf][i][1] * fac;
      w0[2] = (float)cv[hf][i][2] * fac; w0[3] = (float)cv[hf][i][3] * fac;
      w1[0] = (float)cv[hf][i][4] * fac; w1[1] = (float)cv[hf][i][5] * fac;
      w1[2] = (float)cv[hf][i][6] * fac; w1[3] = (float)cv[hf][i][7] * fac;
      __builtin_nontemporal_store(w0, (f32x4v*)(op + i * 8));
      __builtin_nontemporal_store(w1, (f32x4v*)(op + i * 8 + 4));
    }
  }
}

extern "C" void kernel_launch(void* const* d_in, const int* in_sizes, int n_in,
                              void* d_out, int out_size, void* d_ws, size_t ws_size,
                              hipStream_t stream) {
  const float* x       = (const float*)d_in[0];   // [32768, 512] fp32
  const float* centers = (const float*)d_in[1];   // [1024, 512] fp32
  float* out = (float*)d_out;                     // [32768, 1024] fp32

  char* ws = (char*)d_ws;
  f16_t*  bpack = (f16_t*)ws;                          // 1MB
  float*  bias  = (float*)(ws + (1 << 20));            // 4KB
  float2* stats = (float2*)(ws + (1 << 20) + 4096);    // 512KB
  int*    flags = (int*)(ws + (1 << 20) + 4096 + (512 << 10));  // 2KB

  hipMemsetAsync(flags, 0, NTILE * sizeof(int), stream);
  prep_kernel<<<K_CL, 64, 0, stream>>>(centers, bpack, bias);
  cluster_kernel<<<2 * NTILE, THREADS, 0, stream>>>(x, bpack, bias, out,
                                                    stats, flags);
}

// Round 13
// 92.595 us; speedup vs baseline: 3.5572x; 3.5572x over previous
//
#include <hip/hip_runtime.h>
#include <stdint.h>

// ClusterHead: P = softmax_k( x . c_k - 0.5*||c_k||^2 )   (||x||^2 cancels)
// R13: 256-thread blocks (4 waves = 1 wave/SIMD) -> 2 blocks/CU with the
// FULL 256-VGPR budget per wave (R9/R12 spills came from demanding 4
// waves/SIMD of 512-thread blocks = 128-reg cap). Tile 32 rows x 1024 cols,
// wave w covers cols [w*256, +256): acc[8] f32x16 = 128 VGPR. Block-local
// softmax (no cross-block merge). Cross-BLOCK TLP now hides the per-block
// serial chain (stage -> K-loop -> epilogue -> store drain) that R11
// measured as the ~55us constant. Single-term fp16 GEMM (absmax 0.0078),
// 32x32x16 f16 MFMA, A-panel in LDS (XOR swizzle), barrier-free K-loop,
// B double-buffered at ks (half-slice) granularity, NT x-loads/out-stores.
// B-pack: 32 sub-images of 32KB; s = 2T + jh; within: [ks(2)][cb(16)]
// [(c32*2+kh)*8] halfwords.

namespace {
constexpr int N_ROWS  = 32768;
constexpr int K_CL    = 1024;
constexpr int D_DIM   = 512;
constexpr int BM      = 32;
constexpr int THREADS = 256;
constexpr int NSLICE  = 16;     // k-slices of 32
}

typedef _Float16 f16_t;
typedef _Float16 f16x8 __attribute__((ext_vector_type(8)));
typedef _Float16 f16x4 __attribute__((ext_vector_type(4)));
typedef float    f32x16 __attribute__((ext_vector_type(16)));
typedef float    f32x4v __attribute__((ext_vector_type(4)));

// ---- prep: fp16 B-pack + bias = -0.5*||c||^2 (fp32 exact) ----
__global__ __launch_bounds__(64) void prep_kernel(const float* __restrict__ centers,
                                                  f16_t* __restrict__ bpack,
                                                  float* __restrict__ bias) {
  const int col = blockIdx.x, lane = threadIdx.x;
  const int t  = lane >> 2;
  const int ks = (lane >> 1) & 1;
  const int kh = lane & 1;
  const float* src = centers + (size_t)col * D_DIM + lane * 8;
  f16x8 hi;
  float ssq = 0.f;
  #pragma unroll
  for (int i = 0; i < 8; ++i) {
    float v = src[i];
    ssq += v * v;
    hi[i] = (f16_t)v;
  }
  const int jh = col >> 9, cb = (col & 511) >> 5, c32 = col & 31;
  const size_t off = ((size_t)ks * 16 + cb) * 512 + (c32 * 2 + kh) * 8;
  *(f16x8*)(bpack + (size_t)(2 * t + jh) * 16384 + off) = hi;
  for (int o = 32; o; o >>= 1) ssq += __shfl_down(ssq, o, 64);
  if (lane == 0) bias[col] = -0.5f * ssq;
}

// ---- main fused kernel: 32 rows x 1024 cols, 256 threads, 2 blocks/CU ----
__global__ __launch_bounds__(THREADS, 2) void cluster_kernel(
    const float* __restrict__ x, const f16_t* __restrict__ bpack,
    const float* __restrict__ bias, float* __restrict__ out) {
  __shared__ __align__(16) char Ax[32768];   // 32KB swizzled A panel
  __shared__ float red[4 * BM];              // 512B
  __shared__ float fin[BM];

  const int tid  = threadIdx.x;
  const int w    = tid >> 6;       // wave 0..3 -> cols [w*256, +256)
  const int lane = tid & 63;
  const int l31  = lane & 31;
  const int h    = lane >> 5;
  const int brow = blockIdx.x * BM;

  // per-lane base: jh = w>>1 (sub-image select), cb-base = (w&1)*8
  const char* bbase = (const char*)bpack + (w >> 1) * 32768 + (w & 1) * 8192 +
                      (l31 * 2 + h) * 16;

#define LOADB(T, KS, DST)                                                      \
  {                                                                            \
    const char* p_ = bbase + (size_t)(T) * 65536 + (KS) * 16384;               \
    _Pragma("unroll")                                                          \
    for (int cb_ = 0; cb_ < 8; ++cb_)                                          \
      (DST)[cb_] = *(const f16x8*)(p_ + cb_ * 1024);                           \
  }

  f16x8 b0[8], b1[8];
  LOADB(0, 0, b0)   // in flight during A staging

  // ---- stage A panel -> LDS fp16 (coalesced NT reads, swizzled writes) ----
  {
    const float* xsrc = x + (size_t)brow * D_DIM;
    #pragma unroll
    for (int it = 0; it < 16; ++it) {
      const int idx = it * 256 + tid;          // float4 index (32*128 total)
      const int r = idx >> 7, f = idx & 127;
      f32x4v v = __builtin_nontemporal_load(
          (const f32x4v*)(xsrc + (size_t)r * D_DIM + f * 4));
      f16x4 h4;
      h4[0] = (f16_t)v[0]; h4[1] = (f16_t)v[1];
      h4[2] = (f16_t)v[2]; h4[3] = (f16_t)v[3];
      *(f16x4*)(Ax + r * 1024 + ((f * 8) ^ ((r & 7) << 4))) = h4;
    }
  }
  __syncthreads();   // the only pre-epilogue barrier

  f32x16 acc[8];
  #pragma unroll
  for (int cb = 0; cb < 8; ++cb)
    #pragma unroll
    for (int e = 0; e < 16; ++e) acc[cb][e] = 0.f;

  const char* abase = Ax + l31 * 1024;
  const int swz = (l31 & 7) << 4;

  // ---- K loop: 16 slices, barrier-free, B double-buffered per ks-half ----
  #pragma unroll
  for (int T = 0; T < NSLICE; ++T) {
    const f16x8 a0 = *(const f16x8*)(abase + ((T * 64 + h * 16) ^ swz));
    const f16x8 a1 = *(const f16x8*)(abase + ((T * 64 + 32 + h * 16) ^ swz));
    LOADB(T, 1, b1)
    #pragma unroll
    for (int cb = 0; cb < 8; ++cb)
      acc[cb] = __builtin_amdgcn_mfma_f32_32x32x16_f16(a0, b0[cb], acc[cb],
                                                       0, 0, 0);
    if (T < 15) { LOADB(T + 1, 0, b0) }
    #pragma unroll
    for (int cb = 0; cb < 8; ++cb)
      acc[cb] = __builtin_amdgcn_mfma_f32_32x32x16_f16(a1, b1[cb], acc[cb],
                                                       0, 0, 0);
  }

  // ---- epilogue: fused softmax over 1024 columns ----
  // col(cb) = w*256 + cb*32 + l31 ; row(reg) = (reg&3) + 8*(reg>>2) + 4*h
  float bcol[8];
  #pragma unroll
  for (int cb = 0; cb < 8; ++cb)
    bcol[cb] = bias[w * 256 + cb * 32 + l31];

  float rr[16];
  #pragma unroll
  for (int reg = 0; reg < 16; ++reg) {
    float m = -3.0e38f;
    #pragma unroll
    for (int cb = 0; cb < 8; ++cb) {
      float v = acc[cb][reg] + bcol[cb];
      acc[cb][reg] = v;
      m = fmaxf(m, v);
    }
    m = fmaxf(m, __shfl_xor(m, 1, 64));
    m = fmaxf(m, __shfl_xor(m, 2, 64));
    m = fmaxf(m, __shfl_xor(m, 4, 64));
    m = fmaxf(m, __shfl_xor(m, 8, 64));
    m = fmaxf(m, __shfl_xor(m, 16, 64));
    rr[reg] = m;
  }
  if (l31 == 0) {   // lanes 0 and 32 cover distinct rows
    #pragma unroll
    for (int reg = 0; reg < 16; ++reg)
      red[w * BM + (reg & 3) + 8 * (reg >> 2) + 4 * h] = rr[reg];
  }
  __syncthreads();
  if (tid < BM) {
    float m = red[tid];
    #pragma unroll
    for (int ww = 1; ww < 4; ++ww) m = fmaxf(m, red[ww * BM + tid]);
    fin[tid] = m;
  }
  __syncthreads();

  #pragma unroll
  for (int reg = 0; reg < 16; ++reg) {
    const float m = fin[(reg & 3) + 8 * (reg >> 2) + 4 * h];
    float s = 0.f;
    #pragma unroll
    for (int cb = 0; cb < 8; ++cb) {
      float e = __expf(acc[cb][reg] - m);
      acc[cb][reg] = e;
      s += e;
    }
    s += __shfl_xor(s, 1, 64);
    s += __shfl_xor(s, 2, 64);
    s += __shfl_xor(s, 4, 64);
    s += __shfl_xor(s, 8, 64);
    s += __shfl_xor(s, 16, 64);
    rr[reg] = s;
  }
  __syncthreads();   // fin(max) reads done before red overwrite
  if (l31 == 0) {
    #pragma unroll
    for (int reg = 0; reg < 16; ++reg)
      red[w * BM + (reg & 3) + 8 * (reg >> 2) + 4 * h] = rr[reg];
  }
  __syncthreads();
  if (tid < BM) {
    float s = 0.f;
    #pragma unroll
    for (int ww = 0; ww < 4; ++ww) s += red[ww * BM + tid];
    fin[tid] = 1.0f / s;
  }
  __syncthreads();

  #pragma unroll
  for (int reg = 0; reg < 16; ++reg) {
    const int row = (reg & 3) + 8 * (reg >> 2) + 4 * h;
    const float rs = fin[row];
    #pragma unroll
    for (int cb = 0; cb < 8; ++cb) {
      const int col = w * 256 + cb * 32 + l31;
      __builtin_nontemporal_store(acc[cb][reg] * rs,
                                  &out[(size_t)(brow + row) * K_CL + col]);
    }
  }
}

extern "C" void kernel_launch(void* const* d_in, const int* in_sizes, int n_in,
                              void* d_out, int out_size, void* d_ws, size_t ws_size,
                              hipStream_t stream) {
  const float* x       = (const float*)d_in[0];   // [32768, 512] fp32
  const float* centers = (const float*)d_in[1];   // [1024, 512] fp32
  float* out = (float*)d_out;                     // [32768, 1024] fp32

  f16_t* bpack = (f16_t*)d_ws;                                   // 32*32KB = 1MB
  float* bias  = (float*)((char*)d_ws + (size_t)32 * 32768);     // 4KB

  prep_kernel<<<K_CL, 64, 0, stream>>>(centers, bpack, bias);
  cluster_kernel<<<N_ROWS / BM, THREADS, 0, stream>>>(x, bpack, bias, out);
}